// Round 12
// baseline (665.134 us; speedup 1.0000x reference)
//
#include <hip/hip_runtime.h>
#include <stdint.h>

#define NN    6000
#define KNNC  10
#define MM    (NN * 2 * (KNNC + 1))   // 132000
#define DD    (2 * NN)                // 12000
#define LCH   3                       // hidden layers (LC-1)
#define BLK   256

#define RB        256                    // rows per MLP block (4 waves x 64)
#define MLPGRID   ((MM + RB - 1) / RB)   // 516
#define SCGRID    ((MM + BLK - 1) / BLK) // 516
#define OUTBYTES  ((size_t)DD * DD * 4)  // 576,000,000
#define KP        72                     // k-dim padded +8: b128 reads 2-way only

// Round-12: the MLP moves to matrix cores. 11 rounds pinned the scalar-FMA
// MLP at ~150us (vs 21us VALU floor) regardless of weight path/occupancy/
// overlap structure; MfmaUtil was 0% in every profile while the op is a
// [132000x64]x[64x64]x3 GEMM. fp32 -> split-bf16 (hi+lo, RNE): 3 MFMA
// passes hi*hi + hi*lo + lo*hi, fp32 accumulate; dropped lo*lo <= 2^-16
// rel -> abs err ~1e-4 vs 1.8e-3 threshold. Layouts (guide-verified):
// C/D col=lane&15,row=4*(lane>>4)+reg [m89]; A row=lane&15,k=8*(lane>>4)+i;
// B col=lane&15, same k. Per wave: 16-row strips; per strip-layer: 4 A-frag
// + 16 B-frag ds_read_b128 (KP=72 pad -> 2-way bank alias, free) + 24 MFMA.
// Activations LDS round-trip is same-wave -> no barriers after W staging.
// Fill = hipMemsetAsync (94us rocclr path); scatter = unsafeAtomicAdd (~30us).

typedef __attribute__((ext_vector_type(8))) short bf16x8;
typedef __attribute__((ext_vector_type(4))) float f32x4;

__device__ __forceinline__ unsigned short f2bf(float x) {
    unsigned u = __float_as_uint(x);
    u += 0x7FFFu + ((u >> 16) & 1u);      // round-to-nearest-even
    return (unsigned short)(u >> 16);
}
__device__ __forceinline__ float bf2f(unsigned short b) {
    return __uint_as_float((unsigned)b << 16);
}

__global__ __launch_bounds__(BLK, 2) void mlp_mfma(
    const float* __restrict__ CK,    // [MM,3]
    const float* __restrict__ Win,   // [3,64]
    const float* __restrict__ bin,   // [64]
    const float* __restrict__ Whid,  // [3,64,64]
    const float* __restrict__ bhid,  // [3,64]
    const float* __restrict__ Wout,  // [64,4]
    const float* __restrict__ bout,  // [4]
    float* __restrict__ vals)        // [MM,2]
{
    // W transposed [layer][part][j][k(+pad)] bf16: B-frag = 1 b128/lane.
    __shared__ unsigned short sWt[LCH * 2 * 64 * KP];   // 55,296 B
    // Per-wave activation buffer [wave][part][r][k(+pad)] bf16.
    __shared__ unsigned short sA[4 * 2 * 16 * KP];      // 18,432 B

    const int tid  = threadIdx.x;
    const int wave = tid >> 6;
    const int lane = tid & 63;
    const int lr   = lane & 15;     // A-row / B-col / D-col selector
    const int lg   = lane >> 4;     // k-group (8 k's each)

    // ---- stage W hi/lo, transposed (once per block) ----
    for (int idx = tid; idx < LCH * 64 * 64; idx += BLK) {
        const int l = idx >> 12, rem = idx & 4095;
        const int k = rem >> 6, j = rem & 63;          // Whid[l][k][j]
        const float w = Whid[idx];
        const unsigned short hi = f2bf(w);
        sWt[((l * 2 + 0) * 64 + j) * KP + k] = hi;
        sWt[((l * 2 + 1) * 64 + j) * KP + k] = f2bf(w - bf2f(hi));
    }
    __syncthreads();   // only barrier in the kernel

    unsigned short* __restrict__ aH = sA + ((wave * 2 + 0) * 16) * KP;
    unsigned short* __restrict__ aL = sA + ((wave * 2 + 1) * 16) * KP;

    const int wbase = blockIdx.x * RB + wave * 64;

#pragma unroll 1
    for (int s = 0; s < 4; s++) {
        const int rbase = wbase + s * 16;

        // ---- input layer 3->64 (VALU): lane does row lr, channels lg*16.. ----
        {
            int m = rbase + lr; if (m >= MM) m = MM - 1;
            const float x0 = CK[m * 3], x1 = CK[m * 3 + 1], x2 = CK[m * 3 + 2];
            const int j0 = lg * 16;
            bf16x8 hv0, hv1, lv0, lv1;
#pragma unroll
            for (int jj = 0; jj < 16; jj++) {
                const int j = j0 + jj;
                float a = fmaf(x2, Win[128 + j],
                          fmaf(x1, Win[64 + j], fmaf(x0, Win[j], bin[j])));
                a = fmaxf(a, 0.f);
                const unsigned short hi = f2bf(a);
                const unsigned short lo = f2bf(a - bf2f(hi));
                if (jj < 8) { hv0[jj] = (short)hi; lv0[jj] = (short)lo; }
                else        { hv1[jj - 8] = (short)hi; lv1[jj - 8] = (short)lo; }
            }
            *(bf16x8*)(aH + lr * KP + j0)     = hv0;   // 16B-aligned (KP=72)
            *(bf16x8*)(aH + lr * KP + j0 + 8) = hv1;
            *(bf16x8*)(aL + lr * KP + j0)     = lv0;
            *(bf16x8*)(aL + lr * KP + j0 + 8) = lv1;
        }

        f32x4 acc[4];
#pragma unroll 1
        for (int l = 0; l < LCH; l++) {
            // A-frags: row lr, k = kk*32 + lg*8 .. +7 (same-wave RAW on sA).
            bf16x8 a_hi[2], a_lo[2];
#pragma unroll
            for (int kk = 0; kk < 2; kk++) {
                a_hi[kk] = *(const bf16x8*)(aH + lr * KP + kk * 32 + lg * 8);
                a_lo[kk] = *(const bf16x8*)(aL + lr * KP + kk * 32 + lg * 8);
            }
            // bias into fp32 accumulator (col = ct*16+lr, all 4 rows equal)
#pragma unroll
            for (int ct = 0; ct < 4; ct++) {
                const float b = bhid[l * 64 + ct * 16 + lr];
                acc[ct] = (f32x4){b, b, b, b};
            }
#pragma unroll
            for (int ct = 0; ct < 4; ct++) {
                const unsigned short* wH =
                    sWt + ((l * 2 + 0) * 64 + ct * 16 + lr) * KP + lg * 8;
                const unsigned short* wL =
                    sWt + ((l * 2 + 1) * 64 + ct * 16 + lr) * KP + lg * 8;
#pragma unroll
                for (int kk = 0; kk < 2; kk++) {
                    const bf16x8 b_hi = *(const bf16x8*)(wH + kk * 32);
                    const bf16x8 b_lo = *(const bf16x8*)(wL + kk * 32);
                    acc[ct] = __builtin_amdgcn_mfma_f32_16x16x32_bf16(
                                  a_hi[kk], b_hi, acc[ct], 0, 0, 0);
                    acc[ct] = __builtin_amdgcn_mfma_f32_16x16x32_bf16(
                                  a_hi[kk], b_lo, acc[ct], 0, 0, 0);
                    acc[ct] = __builtin_amdgcn_mfma_f32_16x16x32_bf16(
                                  a_lo[kk], b_hi, acc[ct], 0, 0, 0);
                }
            }
            if (l < LCH - 1) {
                // ReLU + hi/lo writeback: lane's D = [row 4*lg+q][col ct*16+lr]
#pragma unroll
                for (int ct = 0; ct < 4; ct++)
#pragma unroll
                for (int q = 0; q < 4; q++) {
                    const float v = fmaxf(acc[ct][q], 0.f);
                    const unsigned short hi = f2bf(v);
                    const int r = lg * 4 + q, k = ct * 16 + lr;
                    aH[r * KP + k] = hi;
                    aL[r * KP + k] = f2bf(v - bf2f(hi));
                }
            }
        }

        // ---- output layer (VALU from acc): v[:,mj] = C[:,mj]+C[:,mj+2] ----
        float v0[4] = {0, 0, 0, 0}, v1[4] = {0, 0, 0, 0};
#pragma unroll
        for (int ct = 0; ct < 4; ct++) {
            const float4 wo = ((const float4*)Wout)[ct * 16 + lr];
            const float wxz = wo.x + wo.z, wyw = wo.y + wo.w;
#pragma unroll
            for (int q = 0; q < 4; q++) {
                const float h = fmaxf(acc[ct][q], 0.f);
                v0[q] = fmaf(h, wxz, v0[q]);
                v1[q] = fmaf(h, wyw, v1[q]);
            }
        }
        // reduce across the 16 lanes of each k-group (rows 4*lg+q)
#pragma unroll
        for (int off = 1; off < 16; off <<= 1) {
#pragma unroll
            for (int q = 0; q < 4; q++) {
                v0[q] += __shfl_xor(v0[q], off);
                v1[q] += __shfl_xor(v1[q], off);
            }
        }
        if (lr == 0) {
            const float b02 = bout[0] + bout[2], b13 = bout[1] + bout[3];
#pragma unroll
            for (int q = 0; q < 4; q++) {
                const int m = rbase + lg * 4 + q;
                if (m < MM)
                    *(float2*)(vals + 2 * m) =
                        make_float2(v0[q] + b02, v1[q] + b13);
            }
        }
    }
}

__global__ __launch_bounds__(BLK) void scatter_add(
    const float* __restrict__ vals,   // [MM,2]
    const int* __restrict__ coo,      // [2,MM]
    float* __restrict__ out)          // [DD*DD]
{
    const int t = blockIdx.x * BLK + threadIdx.x;
    if (t >= MM) return;
    const int r2 = coo[t] * 2;        // row index * MODES
    const int c2 = coo[MM + t] * 2;   // col index * MODES
    const float2 v = *(const float2*)(vals + 2 * t);
    const long long f0 = (long long)r2 * DD + c2;
    // Native global_atomic_add_f32 (fire-and-forget), not a CAS retry loop.
    unsafeAtomicAdd(out + f0, v.x);
    unsafeAtomicAdd(out + f0 + DD + 1, v.y);
}

extern "C" void kernel_launch(void* const* d_in, const int* in_sizes, int n_in,
                              void* d_out, int out_size, void* d_ws, size_t ws_size,
                              hipStream_t stream) {
    const float* CK   = (const float*)d_in[0];
    const float* Win  = (const float*)d_in[1];
    const float* bin  = (const float*)d_in[2];
    const float* Whid = (const float*)d_in[3];
    const float* bhid = (const float*)d_in[4];
    const float* Wout = (const float*)d_in[5];
    const float* bout = (const float*)d_in[6];
    const int* coo    = (const int*)d_in[7];
    float* out        = (float*)d_out;
    float* vals       = (float*)d_ws;

    // 576MB zero on the rocclr fill path (measured 6.15 TB/s on this buffer).
    hipMemsetAsync(out, 0, OUTBYTES, stream);
    mlp_mfma<<<MLPGRID, BLK, 0, stream>>>(
        CK, Win, bin, Whid, bhid, Wout, bout, vals);
    scatter_add<<<SCGRID, BLK, 0, stream>>>(vals, coo, out);
}

// Round 15
// 647.984 us; speedup vs baseline: 1.0265x; 1.0265x over previous
//
#include <hip/hip_runtime.h>
#include <stdint.h>

#define NN    6000
#define KNNC  10
#define MM    (NN * 2 * (KNNC + 1))   // 132000
#define DD    (2 * NN)                // 12000
#define LCH   3                       // hidden layers (LC-1)
#define BLK   256

#define RB     128                     // rows per MLP block
#define RPL    2                       // rows per lane
#define MLPGRID ((MM + RB - 1) / RB)   // 1032
#define SCGRID  ((MM + BLK - 1) / BLK) // 516 (fallback)
#define OUTBYTES ((size_t)DD * DD * 4) // 576,000,000

#define MAXB     128                   // bucket capacity (avg load 22, max ~43)
#define VALS_B   (MM * 2 * 4)          // 1,056,000
#define CNT_B    (NN * 4)              // 24,000
#define BINS_B   (NN * MAXB * 4)       // 3,072,000
#define WS_NEEDED (VALS_B + CNT_B + BINS_B)   // 4,152,000

// Round-15 = Round-13/14 resubmitted (both died at container acquisition:
// no timing dict, no compile, no absmax -> infra, kernel never ran).
// De-risk delta vs R14: the workspace hipMemsetAsync (only new host-API
// usage vs the R8-R12 kernels that ran fine) is replaced by a trivial
// zero_cnt kernel; everything else identical.
// Theory (untested, unchanged): ledger re-audit says the ~120us pig is the
// scatter's random-line HBM RMW drain (R2 direct: CAS scatter=126; native
// atomics can't be slower than CAS on the same pattern), with memset 94,
// mlp_R9 ~55 -- why no MLP rewrite ever moved the total. Fix: never
// scatter into HBM. (1) mlp_bin = R9's proven s_load-lockstep body +
// epilogue binning by destination row i=coo0 (24KB L2-hot counter, 3MB
// L2-resident bins); (2) fill_place: block i builds output rows 2i/2i+1 in
// a 48KB LDS row buffer (zero -> LDS-atomic place ~22 entries -> stream
// 48KB full-line float4), 3 blocks/CU. No out-memset, no global atomics.

__global__ void zero_cnt(int* __restrict__ cnt) {
    const int i = blockIdx.x * BLK + threadIdx.x;
    if (i < NN) cnt[i] = 0;
}

__global__ __launch_bounds__(BLK, 4) void mlp_bin(
    const float* __restrict__ CK,    // [MM,3]
    const float* __restrict__ Win,   // [3,64]
    const float* __restrict__ bin,   // [64]
    const float* __restrict__ Whid,  // [3,64,64]
    const float* __restrict__ bhid,  // [3,64]
    const float* __restrict__ Wout,  // [64,4]
    const float* __restrict__ bout,  // [4]
    const int* __restrict__ coo,     // [2,MM]
    float* __restrict__ vals,        // [MM,2]
    int* __restrict__ cnt,           // [NN] (pre-zeroed) or null
    int* __restrict__ bins,          // [NN,MAXB] or null
    const int do_bins)
{
    __shared__ float sH[64 * RB];    // activations [k][row], row=lane*2+r, 32 KiB

    const int tid  = threadIdx.x;
    const int wave = tid >> 6;
    const int lane = tid & 63;
    // Wave-uniform channel offset in an SGPR -> weight loads scalarize.
    const int jo = __builtin_amdgcn_readfirstlane((tid >> 6) << 4);

    const int rbase = blockIdx.x * RB;
    const int mb0   = rbase + lane * 2;        // lane's first row (even)
    const int mb    = mb0 < MM ? mb0 : MM - 2; // clamp loads, guard stores

    // Lane's 2 rows of inputs: 6 consecutive floats -> 3 float2.
    const float2 ca = *(const float2*)(CK + mb * 3);      // x0r0 x1r0
    const float2 cb = *(const float2*)(CK + mb * 3 + 2);  // x2r0 x0r1
    const float2 cc = *(const float2*)(CK + mb * 3 + 4);  // x1r1 x2r1
    const float x0[RPL] = {ca.x, cb.y};
    const float x1[RPL] = {ca.y, cc.x};
    const float x2[RPL] = {cb.x, cc.y};

    // Input layer: this wave's 16 channels for its 2 packed rows.
#pragma unroll
    for (int jj = 0; jj < 16; jj++) {
        const int j = jo + jj;
        const float w0 = Win[j], w1 = Win[64 + j], w2 = Win[128 + j];  // s_load
        const float bj = bin[j];
        float2 hv;
        hv.x = fmaxf(fmaf(x2[0], w2, fmaf(x1[0], w1, fmaf(x0[0], w0, bj))), 0.f);
        hv.y = fmaxf(fmaf(x2[1], w2, fmaf(x1[1], w1, fmaf(x0[1], w0, bj))), 0.f);
        *(float2*)(sH + j * RB + lane * 2) = hv;
    }
    __syncthreads();

    // Hidden layers, barrier-lockstep (all waves on the same 16KB W -> K$-hot).
#pragma unroll 1
    for (int l = 0; l < LCH; l++) {
        const float* __restrict__ Wl = Whid + (l << 12) + jo;  // uniform SGPR base
        const float* __restrict__ bh = bhid + (l << 6) + jo;

        float g[RPL][16];
#pragma unroll
        for (int jj = 0; jj < 16; jj++) {
            const float bj = bh[jj];           // s_load
            g[0][jj] = bj;
            g[1][jj] = bj;
        }

#pragma unroll 4
        for (int k = 0; k < 64; k++) {
            // This wave's 16-channel weight slice: 64B uniform -> s_load.
            const float4 wa = *(const float4*)(Wl + (k << 6));
            const float4 wb = *(const float4*)(Wl + (k << 6) + 4);
            const float4 wc = *(const float4*)(Wl + (k << 6) + 8);
            const float4 wd = *(const float4*)(Wl + (k << 6) + 12);
            const float2 hv = *(const float2*)(sH + k * RB + lane * 2);
            const float hk[RPL] = {hv.x, hv.y};
#pragma unroll
            for (int r = 0; r < RPL; r++) {
                g[r][0]  = fmaf(wa.x, hk[r], g[r][0]);
                g[r][1]  = fmaf(wa.y, hk[r], g[r][1]);
                g[r][2]  = fmaf(wa.z, hk[r], g[r][2]);
                g[r][3]  = fmaf(wa.w, hk[r], g[r][3]);
                g[r][4]  = fmaf(wb.x, hk[r], g[r][4]);
                g[r][5]  = fmaf(wb.y, hk[r], g[r][5]);
                g[r][6]  = fmaf(wb.z, hk[r], g[r][6]);
                g[r][7]  = fmaf(wb.w, hk[r], g[r][7]);
                g[r][8]  = fmaf(wc.x, hk[r], g[r][8]);
                g[r][9]  = fmaf(wc.y, hk[r], g[r][9]);
                g[r][10] = fmaf(wc.z, hk[r], g[r][10]);
                g[r][11] = fmaf(wc.w, hk[r], g[r][11]);
                g[r][12] = fmaf(wd.x, hk[r], g[r][12]);
                g[r][13] = fmaf(wd.y, hk[r], g[r][13]);
                g[r][14] = fmaf(wd.z, hk[r], g[r][14]);
                g[r][15] = fmaf(wd.w, hk[r], g[r][15]);
            }
        }
        __syncthreads();   // all reads of sH for layer l complete

        // relu + writeback: 16 b64 (2 packed rows per channel).
#pragma unroll
        for (int jj = 0; jj < 16; jj++) {
            float2 hv;
            hv.x = fmaxf(g[0][jj], 0.f);
            hv.y = fmaxf(g[1][jj], 0.f);
            *(float2*)(sH + (jo + jj) * RB + lane * 2) = hv;
        }
        __syncthreads();   // h ready for next layer / output
    }

    // Output layer collapsed over mi: v[:,mj] = C[:,mj] + C[:,mj+2].
    float v0[RPL], v1[RPL];
    const float b02 = bout[0] + bout[2], b13 = bout[1] + bout[3];
#pragma unroll
    for (int r = 0; r < RPL; r++) { v0[r] = b02; v1[r] = b13; }
#pragma unroll 8
    for (int k = 0; k < 64; k++) {
        const float4 wo = ((const float4*)Wout)[k];     // s_load
        const float wxz = wo.x + wo.z, wyw = wo.y + wo.w;
        const float2 hv = *(const float2*)(sH + k * RB + lane * 2);
        v0[0] = fmaf(hv.x, wxz, v0[0]);  v1[0] = fmaf(hv.x, wyw, v1[0]);
        v0[1] = fmaf(hv.y, wxz, v0[1]);  v1[1] = fmaf(hv.y, wyw, v1[1]);
    }
    if (wave == 0 && mb0 < MM) {
        *(float4*)(vals + 2 * mb0) = make_float4(v0[0], v1[0], v0[1], v1[1]);
        if (do_bins) {
            // Bin both rows by destination row index i = coo0[m]. cnt is a
            // 24KB L2-hot array; bins is 3MB L2-resident -> fast atomics.
#pragma unroll
            for (int r = 0; r < RPL; r++) {
                const int m = mb0 + r;
                const int i = coo[m];
                const int pos = atomicAdd(&cnt[i], 1);
                if (pos < MAXB) bins[i * MAXB + pos] = m;
            }
        }
    }
}

// Block i builds output rows 2i and 2i+1 entirely in LDS, then streams
// them out as full-line float4 stores: the "scatter" costs zero extra HBM
// traffic and zero global atomics.
__global__ __launch_bounds__(BLK, 3) void fill_place(
    const float* __restrict__ vals,   // [MM,2]
    const int* __restrict__ coo,      // [2,MM]
    const int* __restrict__ cnt,      // [NN]
    const int* __restrict__ bins,     // [NN,MAXB]
    float* __restrict__ out)          // [DD*DD]
{
    __shared__ float row[DD];          // one output row, 48,000 B

    const int i   = blockIdx.x;        // 0..NN-1
    const int tid = threadIdx.x;
    int n = cnt[i];
    if (n > MAXB) n = MAXB;
    if (n < 0)    n = 0;

#pragma unroll 1
    for (int mj = 0; mj < 2; mj++) {
        // zero the LDS row (coalesced b128)
        float4 z = make_float4(0.f, 0.f, 0.f, 0.f);
        for (int j = tid; j < DD / 4; j += BLK) ((float4*)row)[j] = z;
        __syncthreads();
        // place this row's couplings (avg ~22; LDS atomics handle dups)
        for (int e = tid; e < n; e += BLK) {
            const int m = bins[i * MAXB + e];
            const int c = coo[MM + m] * 2 + mj;
            atomicAdd(&row[c], vals[2 * m + mj]);
        }
        __syncthreads();
        // stream the finished row to HBM (full-line stores)
        float4* __restrict__ dst = (float4*)(out + (size_t)(2 * i + mj) * DD);
        for (int j = tid; j < DD / 4; j += BLK) dst[j] = ((const float4*)row)[j];
        __syncthreads();   // row[] reads done before next mj re-zeroes
    }
}

__global__ __launch_bounds__(BLK) void scatter_add(   // fallback path
    const float* __restrict__ vals, const int* __restrict__ coo,
    float* __restrict__ out)
{
    const int t = blockIdx.x * BLK + threadIdx.x;
    if (t >= MM) return;
    const int r2 = coo[t] * 2;
    const int c2 = coo[MM + t] * 2;
    const float2 v = *(const float2*)(vals + 2 * t);
    const long long f0 = (long long)r2 * DD + c2;
    unsafeAtomicAdd(out + f0, v.x);
    unsafeAtomicAdd(out + f0 + DD + 1, v.y);
}

extern "C" void kernel_launch(void* const* d_in, const int* in_sizes, int n_in,
                              void* d_out, int out_size, void* d_ws, size_t ws_size,
                              hipStream_t stream) {
    const float* CK   = (const float*)d_in[0];
    const float* Win  = (const float*)d_in[1];
    const float* bin  = (const float*)d_in[2];
    const float* Whid = (const float*)d_in[3];
    const float* bhid = (const float*)d_in[4];
    const float* Wout = (const float*)d_in[5];
    const float* bout = (const float*)d_in[6];
    const int* coo    = (const int*)d_in[7];
    float* out        = (float*)d_out;
    float* vals       = (float*)d_ws;

    if (ws_size >= (size_t)WS_NEEDED) {
        int* cnt  = (int*)((char*)d_ws + VALS_B);
        int* bins = (int*)((char*)d_ws + VALS_B + CNT_B);
        zero_cnt<<<(NN + BLK - 1) / BLK, BLK, 0, stream>>>(cnt);
        mlp_bin<<<MLPGRID, BLK, 0, stream>>>(
            CK, Win, bin, Whid, bhid, Wout, bout, coo, vals, cnt, bins, 1);
        fill_place<<<NN, BLK, 0, stream>>>(vals, coo, cnt, bins, out);
    } else {
        // Fallback (small ws): R9 structure — memset + mlp + atomic scatter.
        hipMemsetAsync(out, 0, OUTBYTES, stream);
        mlp_bin<<<MLPGRID, BLK, 0, stream>>>(
            CK, Win, bin, Whid, bhid, Wout, bout, coo, vals, nullptr, nullptr, 0);
        scatter_add<<<SCGRID, BLK, 0, stream>>>(vals, coo, out);
    }
}